// Round 4
// baseline (2005.736 us; speedup 1.0000x reference)
//
#include <hip/hip_runtime.h>

// LightGCN-style 3-layer bipartite propagation.
// R3 counters: scatter_kernel 365us (WRITE_SIZE 247MB for 32MB payload: every
// random 8B write pays a 64B HBM line); 3 spmm dispatches ~300us each moving
// ~2GB of 512B gathers. R4: (a) two-phase binned scatter (multisplit into
// 256-row buckets, then LDS-cursor scatter confined to L2-resident spans);
// (b) bf16 gather tables (halve gather bytes; fp32 accumulation + fp32 sum
// chain preserved; layer-3 dst store skipped).

#define NUM_USERS 100000
#define NUM_ITEMS 50000
#define EMBED_DIM 128
#define NNZ_COUNT 2000000
#define SCAN_CHUNK 4096
#define NBUCK_U 391   // ceil(100000/256)
#define NBUCK_I 196   // ceil(50000/256)

// ---------------- bf16 helpers (manual RTNE) ----------------

__device__ __forceinline__ unsigned bf16_rnd(float f) {
    unsigned u = __float_as_uint(f);
    return (u + 0x7FFFu + ((u >> 16) & 1u)) >> 16;
}
__device__ __forceinline__ unsigned pack_bf16(float x, float y) {
    return bf16_rnd(x) | (bf16_rnd(y) << 16);
}

// fp32 table -> packed bf16 (2 per uint). n8 = n/8 (n divisible by 8).
__global__ __launch_bounds__(256) void to_bf16_kernel(
    const float* __restrict__ a, unsigned* __restrict__ o, int n8)
{
    int i = blockIdx.x * 256 + threadIdx.x;
    if (i >= n8) return;
    const float4* a4 = reinterpret_cast<const float4*>(a);
    float4 x = a4[i * 2], y = a4[i * 2 + 1];
    uint4 r;
    r.x = pack_bf16(x.x, x.y); r.y = pack_bf16(x.z, x.w);
    r.z = pack_bf16(y.x, y.y); r.w = pack_bf16(y.z, y.w);
    reinterpret_cast<uint4*>(o)[i] = r;
}

// ---------------- CSR build ----------------

__global__ __launch_bounds__(256) void histo_kernel(
    const int* __restrict__ rows, const int* __restrict__ cols,
    int* __restrict__ cnt_u, int* __restrict__ cnt_i, int nnz)
{
    int e = blockIdx.x * blockDim.x + threadIdx.x;
    if (e >= nnz) return;
    atomicAdd(&cnt_u[rows[e]], 1);
    atomicAdd(&cnt_i[cols[e]], 1);
}

__global__ __launch_bounds__(256) void scan_partial_sums(
    const int* __restrict__ cnt, int* __restrict__ partials, int n)
{
    const int base = blockIdx.x * SCAN_CHUNK;
    int s = 0;
    for (int i = threadIdx.x; i < SCAN_CHUNK; i += 256) {
        const int idx = base + i;
        if (idx < n) s += cnt[idx];
    }
    for (int d = 32; d; d >>= 1) s += __shfl_down(s, d);
    __shared__ int red[4];
    if ((threadIdx.x & 63) == 0) red[threadIdx.x >> 6] = s;
    __syncthreads();
    if (threadIdx.x == 0) partials[blockIdx.x] = red[0] + red[1] + red[2] + red[3];
}

__global__ void scan_partials_kernel(int* __restrict__ partials,
                                     int* __restrict__ ptr_n, int nb)
{
    if (threadIdx.x == 0) {
        int run = 0;
        for (int b = 0; b < nb; ++b) { int x = partials[b]; partials[b] = run; run += x; }
        *ptr_n = run;
    }
}

__global__ __launch_bounds__(256) void scan_chunk_kernel(
    int* __restrict__ cnt, const int* __restrict__ partials,
    int* __restrict__ ptr, int n)
{
    __shared__ int tsum[256];
    const int t = threadIdx.x;
    const int base = blockIdx.x * SCAN_CHUNK + t * 16;
    int v[16];
    int s = 0;
    for (int k = 0; k < 16; ++k) {
        const int idx = base + k;
        v[k] = (idx < n) ? cnt[idx] : 0;
        s += v[k];
    }
    tsum[t] = s;
    __syncthreads();
    for (int d = 1; d < 256; d <<= 1) {
        const int y = (t >= d) ? tsum[t - d] : 0;
        __syncthreads();
        tsum[t] += y;
        __syncthreads();
    }
    int off = partials[blockIdx.x] + tsum[t] - s;
    for (int k = 0; k < 16; ++k) {
        const int idx = base + k;
        if (idx < n) ptr[idx] = off;
        off += v[k];
    }
}

// ---------------- two-phase binned scatter ----------------
// Bucket = 256 consecutive dst rows. Bucket cursor starts at the bucket's CSR
// base, so the staging region of bucket b is exactly its CSR range.

__global__ __launch_bounds__(256) void init_cursors(
    const int* __restrict__ ptr_u, const int* __restrict__ ptr_i,
    int* __restrict__ gcur_u, int* __restrict__ gcur_i)
{
    int t = blockIdx.x * 256 + threadIdx.x;
    if (t < NBUCK_U) gcur_u[t] = ptr_u[t << 8];
    if (t < NBUCK_I) gcur_i[t] = ptr_i[t << 8];
}

// Phase A: append (packed locator, val) into the dst bucket's staging range.
// u-side pack: col (16b) | local_row (8b) << 16 ; i-side: row (17b) | local_col (8b) << 17.
__global__ __launch_bounds__(256) void bucket_split(
    const int* __restrict__ rows, const int* __restrict__ cols,
    const float* __restrict__ vals,
    int* __restrict__ gcur_u, int* __restrict__ gcur_i,
    int2* __restrict__ stage_u, int2* __restrict__ stage_i, int nnz)
{
    int e = blockIdx.x * 256 + threadIdx.x;
    if (e >= nnz) return;
    const int r = rows[e];
    const int c = cols[e];
    const int vb = __float_as_int(vals[e]);
    const int pu = atomicAdd(&gcur_u[r >> 8], 1);
    stage_u[pu] = make_int2(c | ((r & 255) << 16), vb);
    const int pi = atomicAdd(&gcur_i[c >> 8], 1);
    stage_i[pi] = make_int2(r | ((c & 255) << 17), vb);
}

// Phase B: one block per bucket; per-row cursors in LDS; writes confined to
// the bucket's ~40-80KB CSR span (L2-resident -> lines fill before eviction).
__global__ __launch_bounds__(256) void bucket_scatter(
    const int* __restrict__ ptr_u, const int2* __restrict__ stage_u,
    int2* __restrict__ pairs_u,
    const int* __restrict__ ptr_i, const int2* __restrict__ stage_i,
    int2* __restrict__ pairs_i)
{
    __shared__ int cur[256];
    const int t = threadIdx.x;
    int b = blockIdx.x;
    const bool uside = (b < NBUCK_U);
    const int* ptr; const int2* stage; int2* pairs; int n;
    if (uside) { ptr = ptr_u; stage = stage_u; pairs = pairs_u; n = NUM_USERS; }
    else       { b -= NBUCK_U; ptr = ptr_i; stage = stage_i; pairs = pairs_i; n = NUM_ITEMS; }
    const int first = b << 8;
    const int last  = min(first + 256, n);
    if (first + t < last) cur[t] = ptr[first + t];
    __syncthreads();
    const int beg = ptr[first];
    const int end = ptr[last];
    for (int idx = beg + t; idx < end; idx += 256) {
        const int2 s = stage[idx];
        const int local   = uside ? ((s.x >> 16) & 255) : ((s.x >> 17) & 255);
        const int payload = uside ? (s.x & 0xFFFF)      : (s.x & 0x1FFFF);
        const int slot = atomicAdd(&cur[local], 1);
        pairs[slot] = make_int2(payload, s.y);
    }
}

// ---------------- SpMM: one 64-lane wave per destination row ----------------
// src is a bf16 table (64 uints = 128 bf16 per row). Lane l owns dims [2l,2l+1].
// acc fp32; sum chain fp32; dst (optional) written back as bf16.

template<bool WRITE_DST, bool HAS_BASE>
__device__ __forceinline__ void spmm_row_bf(
    const int* __restrict__ ptr, const int2* __restrict__ pairs,
    const unsigned* __restrict__ src, unsigned* __restrict__ dst,
    float* __restrict__ sum, const float* __restrict__ base,
    int row, int lane, float scale)
{
    const int start = ptr[row];
    const int end   = ptr[row + 1];
    float2 acc = make_float2(0.f, 0.f);

    for (int chunk = start; chunk < end; chunk += 64) {
        const int idx = chunk + lane;
        int2 p = make_int2(0, 0);
        if (idx < end) p = pairs[idx];
        int m = end - chunk; if (m > 64) m = 64;

        int j = 0;
        for (; j + 4 <= m; j += 4) {
            const int   c0 = __shfl(p.x, j),     c1 = __shfl(p.x, j + 1);
            const int   c2 = __shfl(p.x, j + 2), c3 = __shfl(p.x, j + 3);
            const float v0 = __int_as_float(__shfl(p.y, j));
            const float v1 = __int_as_float(__shfl(p.y, j + 1));
            const float v2 = __int_as_float(__shfl(p.y, j + 2));
            const float v3 = __int_as_float(__shfl(p.y, j + 3));
            const unsigned g0 = src[(size_t)c0 * 64 + lane];
            const unsigned g1 = src[(size_t)c1 * 64 + lane];
            const unsigned g2 = src[(size_t)c2 * 64 + lane];
            const unsigned g3 = src[(size_t)c3 * 64 + lane];
            acc.x += v0 * __uint_as_float(g0 << 16);
            acc.y += v0 * __uint_as_float(g0 & 0xFFFF0000u);
            acc.x += v1 * __uint_as_float(g1 << 16);
            acc.y += v1 * __uint_as_float(g1 & 0xFFFF0000u);
            acc.x += v2 * __uint_as_float(g2 << 16);
            acc.y += v2 * __uint_as_float(g2 & 0xFFFF0000u);
            acc.x += v3 * __uint_as_float(g3 << 16);
            acc.y += v3 * __uint_as_float(g3 & 0xFFFF0000u);
        }
        for (; j < m; ++j) {
            const int   c = __shfl(p.x, j);
            const float v = __int_as_float(__shfl(p.y, j));
            const unsigned g = src[(size_t)c * 64 + lane];
            acc.x += v * __uint_as_float(g << 16);
            acc.y += v * __uint_as_float(g & 0xFFFF0000u);
        }
    }

    if (WRITE_DST) dst[(size_t)row * 64 + lane] = pack_bf16(acc.x, acc.y);

    const size_t o = (size_t)row * EMBED_DIM + (lane << 1);
    float2 bsv;
    if (HAS_BASE) bsv = *reinterpret_cast<const float2*>(base + o);
    else          bsv = *reinterpret_cast<const float2*>(sum + o);
    bsv.x = (bsv.x + acc.x) * scale;
    bsv.y = (bsv.y + acc.y) * scale;
    *reinterpret_cast<float2*>(sum + o) = bsv;
}

template<bool WRITE_DST, bool HAS_BASE>
__global__ __launch_bounds__(256) void csr_spmm_dual_bf(
    const int*  __restrict__ ptr_u, const int2* __restrict__ pairs_u,
    const unsigned* __restrict__ src_u, unsigned* __restrict__ dst_u,
    float* __restrict__ sum_u, const float* __restrict__ base_u,
    const int*  __restrict__ ptr_i, const int2* __restrict__ pairs_i,
    const unsigned* __restrict__ src_i, unsigned* __restrict__ dst_i,
    float* __restrict__ sum_i, const float* __restrict__ base_i,
    int GU, float scale)
{
    const int lane = threadIdx.x & 63;
    const int w = threadIdx.x >> 6;
    if ((int)blockIdx.x < GU) {
        const int row = blockIdx.x * 4 + w;
        if (row < NUM_USERS)
            spmm_row_bf<WRITE_DST, HAS_BASE>(ptr_u, pairs_u, src_u, dst_u, sum_u, base_u, row, lane, scale);
    } else {
        const int row = ((int)blockIdx.x - GU) * 4 + w;
        if (row < NUM_ITEMS)
            spmm_row_bf<WRITE_DST, HAS_BASE>(ptr_i, pairs_i, src_i, dst_i, sum_i, base_i, row, lane, scale);
    }
}

// ---------------- fallback (round-1 atomic path) ----------------

__global__ __launch_bounds__(256) void edge_spmm(
    const float* __restrict__ vals, const int* __restrict__ rows,
    const int* __restrict__ cols, const float* __restrict__ u_src,
    const float* __restrict__ i_src, float* __restrict__ u_dst,
    float* __restrict__ i_dst, int nnz)
{
    const int lane = threadIdx.x & 31;
    const int e = blockIdx.x * 8 + (threadIdx.x >> 5);
    if (e >= nnz) return;
    const float v = vals[e];
    const size_t ro = (size_t)rows[e] * EMBED_DIM + lane * 4;
    const size_t co = (size_t)cols[e] * EMBED_DIM + lane * 4;
    const float4 iv = *reinterpret_cast<const float4*>(i_src + co);
    const float4 uv = *reinterpret_cast<const float4*>(u_src + ro);
    atomicAdd(u_dst + ro + 0, v * iv.x); atomicAdd(u_dst + ro + 1, v * iv.y);
    atomicAdd(u_dst + ro + 2, v * iv.z); atomicAdd(u_dst + ro + 3, v * iv.w);
    atomicAdd(i_dst + co + 0, v * uv.x); atomicAdd(i_dst + co + 1, v * uv.y);
    atomicAdd(i_dst + co + 2, v * uv.z); atomicAdd(i_dst + co + 3, v * uv.w);
}

__global__ __launch_bounds__(256) void acc_scale(
    float* __restrict__ out, const float* __restrict__ x, long n, float scale)
{
    long i = ((long)blockIdx.x * blockDim.x + threadIdx.x) * 4;
    if (i >= n) return;
    float4 o = *reinterpret_cast<float4*>(out + i);
    float4 a = *reinterpret_cast<const float4*>(x + i);
    o.x = (o.x + a.x) * scale; o.y = (o.y + a.y) * scale;
    o.z = (o.z + a.z) * scale; o.w = (o.w + a.w) * scale;
    *reinterpret_cast<float4*>(out + i) = o;
}

// ---------------- launch ----------------

extern "C" void kernel_launch(void* const* d_in, const int* in_sizes, int n_in,
                              void* d_out, int out_size, void* d_ws, size_t ws_size,
                              hipStream_t stream)
{
    const float* user = (const float*)d_in[0];
    const float* item = (const float*)d_in[1];
    const float* vals = (const float*)d_in[2];
    const int*   rows = (const int*)d_in[3];
    const int*   cols = (const int*)d_in[4];

    const size_t UD = (size_t)NUM_USERS * EMBED_DIM;   // 12.8M
    const size_t ID = (size_t)NUM_ITEMS * EMBED_DIM;   //  6.4M

    float* out_u = (float*)d_out;
    float* out_i = out_u + UD;

    // ---- CSR-path workspace layout (bf16 tables as packed uints) ----
    char* ws = (char*)d_ws;
    unsigned* user_bf = (unsigned*)ws;              ws += UD * 2;   // 64 uints/row
    unsigned* item_bf = (unsigned*)ws;              ws += ID * 2;
    unsigned* uA = (unsigned*)ws;                   ws += UD * 2;
    unsigned* uB = (unsigned*)ws;                   ws += UD * 2;
    unsigned* iA = (unsigned*)ws;                   ws += ID * 2;
    unsigned* iB = (unsigned*)ws;                   ws += ID * 2;
    int2* pairs_u = (int2*)ws;                      ws += (size_t)NNZ_COUNT * 8;
    int2* pairs_i = (int2*)ws;                      ws += (size_t)NNZ_COUNT * 8;
    int2* stage_u = (int2*)ws;                      ws += (size_t)NNZ_COUNT * 8;
    int2* stage_i = (int2*)ws;                      ws += (size_t)NNZ_COUNT * 8;
    int* ptr_u = (int*)ws;                          ws += (NUM_USERS + 1) * 4;
    int* cnt_u = (int*)ws;                          ws += NUM_USERS * 4;
    int* ptr_i = (int*)ws;                          ws += (NUM_ITEMS + 1) * 4;
    int* cnt_i = (int*)ws;                          ws += NUM_ITEMS * 4;
    int* part_u = (int*)ws;                         ws += 64 * 4;
    int* part_i = (int*)ws;                         ws += 64 * 4;
    int* gcur_u = (int*)ws;                         ws += 512 * 4;
    int* gcur_i = (int*)ws;                         ws += 512 * 4;
    const size_t REQ = (size_t)(ws - (char*)d_ws);

    const int EB = (NNZ_COUNT + 255) / 256;

    if (ws_size >= REQ) {
        // ---- prep: bf16 copies of the input tables ----
        to_bf16_kernel<<<(int)(UD / 8 / 256), 256, 0, stream>>>(user, user_bf, (int)(UD / 8));
        to_bf16_kernel<<<(int)(ID / 8 / 256), 256, 0, stream>>>(item, item_bf, (int)(ID / 8));

        // ---- CSR build ----
        hipMemsetAsync(cnt_u, 0, NUM_USERS * 4, stream);
        hipMemsetAsync(cnt_i, 0, NUM_ITEMS * 4, stream);
        histo_kernel<<<EB, 256, 0, stream>>>(rows, cols, cnt_u, cnt_i, NNZ_COUNT);

        const int NBU = (NUM_USERS + SCAN_CHUNK - 1) / SCAN_CHUNK;   // 25
        const int NBI = (NUM_ITEMS + SCAN_CHUNK - 1) / SCAN_CHUNK;   // 13
        scan_partial_sums<<<NBU, 256, 0, stream>>>(cnt_u, part_u, NUM_USERS);
        scan_partial_sums<<<NBI, 256, 0, stream>>>(cnt_i, part_i, NUM_ITEMS);
        scan_partials_kernel<<<1, 64, 0, stream>>>(part_u, ptr_u + NUM_USERS, NBU);
        scan_partials_kernel<<<1, 64, 0, stream>>>(part_i, ptr_i + NUM_ITEMS, NBI);
        scan_chunk_kernel<<<NBU, 256, 0, stream>>>(cnt_u, part_u, ptr_u, NUM_USERS);
        scan_chunk_kernel<<<NBI, 256, 0, stream>>>(cnt_i, part_i, ptr_i, NUM_ITEMS);

        // ---- two-phase binned scatter ----
        init_cursors<<<2, 256, 0, stream>>>(ptr_u, ptr_i, gcur_u, gcur_i);
        bucket_split<<<EB, 256, 0, stream>>>(rows, cols, vals, gcur_u, gcur_i,
                                             stage_u, stage_i, NNZ_COUNT);
        bucket_scatter<<<NBUCK_U + NBUCK_I, 256, 0, stream>>>(
            ptr_u, stage_u, pairs_u, ptr_i, stage_i, pairs_i);

        const int GU = (NUM_USERS + 3) / 4;   // 25000
        const int GI = (NUM_ITEMS + 3) / 4;   // 12500

        // layer 1: src = bf16 inputs; sum initialized from fp32 base (fused copy)
        csr_spmm_dual_bf<true, true><<<GU + GI, 256, 0, stream>>>(
            ptr_u, pairs_u, item_bf, uA, out_u, user,
            ptr_i, pairs_i, user_bf, iA, out_i, item, GU, 1.0f);
        // layer 2
        csr_spmm_dual_bf<true, false><<<GU + GI, 256, 0, stream>>>(
            ptr_u, pairs_u, iA, uB, out_u, nullptr,
            ptr_i, pairs_i, uA, iB, out_i, nullptr, GU, 1.0f);
        // layer 3: no dst store needed; fold final /4
        csr_spmm_dual_bf<false, false><<<GU + GI, 256, 0, stream>>>(
            ptr_u, pairs_u, iB, uA, out_u, nullptr,
            ptr_i, pairs_i, uB, iA, out_i, nullptr, GU, 0.25f);
    } else {
        // ---- fallback: round-1 atomic path (fp32 buffers carved from ws) ----
        char* fw = (char*)d_ws;
        float* fuA = (float*)fw;                    fw += UD * 4;
        float* fuB = (float*)fw;                    fw += UD * 4;
        float* fiA = (float*)fw;                    fw += ID * 4;
        float* fiB = (float*)fw;                    fw += ID * 4;

        const int EDGE_BLOCKS = (NNZ_COUNT + 7) / 8;
        const int ACC_U = (int)(UD / 1024), ACC_I = (int)(ID / 1024);

        hipMemcpyAsync(out_u, user, UD * 4, hipMemcpyDeviceToDevice, stream);
        hipMemcpyAsync(out_i, item, ID * 4, hipMemcpyDeviceToDevice, stream);

        hipMemsetAsync(fuA, 0, UD * 4, stream);
        hipMemsetAsync(fiA, 0, ID * 4, stream);
        edge_spmm<<<EDGE_BLOCKS, 256, 0, stream>>>(vals, rows, cols, user, item, fuA, fiA, NNZ_COUNT);
        acc_scale<<<ACC_U, 256, 0, stream>>>(out_u, fuA, (long)UD, 1.0f);
        acc_scale<<<ACC_I, 256, 0, stream>>>(out_i, fiA, (long)ID, 1.0f);

        hipMemsetAsync(fuB, 0, UD * 4, stream);
        hipMemsetAsync(fiB, 0, ID * 4, stream);
        edge_spmm<<<EDGE_BLOCKS, 256, 0, stream>>>(vals, rows, cols, fuA, fiA, fuB, fiB, NNZ_COUNT);
        acc_scale<<<ACC_U, 256, 0, stream>>>(out_u, fuB, (long)UD, 1.0f);
        acc_scale<<<ACC_I, 256, 0, stream>>>(out_i, fiB, (long)ID, 1.0f);

        hipMemsetAsync(fuA, 0, UD * 4, stream);
        hipMemsetAsync(fiA, 0, ID * 4, stream);
        edge_spmm<<<EDGE_BLOCKS, 256, 0, stream>>>(vals, rows, cols, fuB, fiB, fuA, fiA, NNZ_COUNT);
        acc_scale<<<ACC_U, 256, 0, stream>>>(out_u, fuA, (long)UD, 0.25f);
        acc_scale<<<ACC_I, 256, 0, stream>>>(out_i, fiA, (long)ID, 0.25f);
    }
}

// Round 5
// 1112.814 us; speedup vs baseline: 1.8024x; 1.8024x over previous
//
#include <hip/hip_runtime.h>

// LightGCN-style 3-layer bipartite propagation.
// R4 post-mortem: bucket_split's 587 global cursors = atomic-contention cliff
// (1222us, 152GB/s, VALUBusy 0.09%). Revert to R3's per-row-cursor scatter
// (150k cursors, measured ~365us). Keep R4's bf16 gather SpMM (fp32 accum,
// fp32 sum chain, layer-3 dst store skipped) which saved ~350us.

#define NUM_USERS 100000
#define NUM_ITEMS 50000
#define EMBED_DIM 128
#define NNZ_COUNT 2000000
#define SCAN_CHUNK 4096

// ---------------- bf16 helpers (manual RTNE) ----------------

__device__ __forceinline__ unsigned bf16_rnd(float f) {
    unsigned u = __float_as_uint(f);
    return (u + 0x7FFFu + ((u >> 16) & 1u)) >> 16;
}
__device__ __forceinline__ unsigned pack_bf16(float x, float y) {
    return bf16_rnd(x) | (bf16_rnd(y) << 16);
}

// fp32 table -> packed bf16 (2 per uint). n8 = n/8 (n divisible by 8).
__global__ __launch_bounds__(256) void to_bf16_kernel(
    const float* __restrict__ a, unsigned* __restrict__ o, int n8)
{
    int i = blockIdx.x * 256 + threadIdx.x;
    if (i >= n8) return;
    const float4* a4 = reinterpret_cast<const float4*>(a);
    float4 x = a4[i * 2], y = a4[i * 2 + 1];
    uint4 r;
    r.x = pack_bf16(x.x, x.y); r.y = pack_bf16(x.z, x.w);
    r.z = pack_bf16(y.x, y.y); r.w = pack_bf16(y.z, y.w);
    reinterpret_cast<uint4*>(o)[i] = r;
}

// ---------------- CSR build ----------------

__global__ __launch_bounds__(256) void histo_kernel(
    const int* __restrict__ rows, const int* __restrict__ cols,
    int* __restrict__ cnt_u, int* __restrict__ cnt_i, int nnz)
{
    int e = blockIdx.x * blockDim.x + threadIdx.x;
    if (e >= nnz) return;
    atomicAdd(&cnt_u[rows[e]], 1);
    atomicAdd(&cnt_i[cols[e]], 1);
}

__global__ __launch_bounds__(256) void scan_partial_sums(
    const int* __restrict__ cnt, int* __restrict__ partials, int n)
{
    const int base = blockIdx.x * SCAN_CHUNK;
    int s = 0;
    for (int i = threadIdx.x; i < SCAN_CHUNK; i += 256) {
        const int idx = base + i;
        if (idx < n) s += cnt[idx];
    }
    for (int d = 32; d; d >>= 1) s += __shfl_down(s, d);
    __shared__ int red[4];
    if ((threadIdx.x & 63) == 0) red[threadIdx.x >> 6] = s;
    __syncthreads();
    if (threadIdx.x == 0) partials[blockIdx.x] = red[0] + red[1] + red[2] + red[3];
}

__global__ void scan_partials_kernel(int* __restrict__ partials,
                                     int* __restrict__ ptr_n, int nb)
{
    if (threadIdx.x == 0) {
        int run = 0;
        for (int b = 0; b < nb; ++b) { int x = partials[b]; partials[b] = run; run += x; }
        *ptr_n = run;
    }
}

// Writes ptr[] and the scatter cursor in-place into cnt[].
__global__ __launch_bounds__(256) void scan_chunk_kernel(
    int* __restrict__ cnt, const int* __restrict__ partials,
    int* __restrict__ ptr, int n)
{
    __shared__ int tsum[256];
    const int t = threadIdx.x;
    const int base = blockIdx.x * SCAN_CHUNK + t * 16;
    int v[16];
    int s = 0;
    for (int k = 0; k < 16; ++k) {
        const int idx = base + k;
        v[k] = (idx < n) ? cnt[idx] : 0;
        s += v[k];
    }
    tsum[t] = s;
    __syncthreads();
    for (int d = 1; d < 256; d <<= 1) {
        const int y = (t >= d) ? tsum[t - d] : 0;
        __syncthreads();
        tsum[t] += y;
        __syncthreads();
    }
    int off = partials[blockIdx.x] + tsum[t] - s;
    for (int k = 0; k < 16; ++k) {
        const int idx = base + k;
        if (idx < n) { ptr[idx] = off; cnt[idx] = off; }
        off += v[k];
    }
}

// Per-row cursors (150k counters -> low contention; measured ~365us in R3).
__global__ __launch_bounds__(256) void scatter_kernel(
    const int* __restrict__ rows, const int* __restrict__ cols,
    const float* __restrict__ vals,
    int* __restrict__ off_u, int* __restrict__ off_i,
    int2* __restrict__ pairs_u, int2* __restrict__ pairs_i, int nnz)
{
    int e = blockIdx.x * blockDim.x + threadIdx.x;
    if (e >= nnz) return;
    const int r = rows[e];
    const int c = cols[e];
    const int vb = __float_as_int(vals[e]);
    const int pu = atomicAdd(&off_u[r], 1);
    pairs_u[pu] = make_int2(c, vb);
    const int pi = atomicAdd(&off_i[c], 1);
    pairs_i[pi] = make_int2(r, vb);
}

// ---------------- SpMM: one 64-lane wave per destination row ----------------
// src is a bf16 table (64 uints = 128 bf16 per row). Lane l owns dims [2l,2l+1].
// acc fp32; sum chain fp32; dst (optional) written back as bf16.

template<bool WRITE_DST, bool HAS_BASE>
__device__ __forceinline__ void spmm_row_bf(
    const int* __restrict__ ptr, const int2* __restrict__ pairs,
    const unsigned* __restrict__ src, unsigned* __restrict__ dst,
    float* __restrict__ sum, const float* __restrict__ base,
    int row, int lane, float scale)
{
    const int start = ptr[row];
    const int end   = ptr[row + 1];
    float2 acc = make_float2(0.f, 0.f);

    for (int chunk = start; chunk < end; chunk += 64) {
        const int idx = chunk + lane;
        int2 p = make_int2(0, 0);
        if (idx < end) p = pairs[idx];
        int m = end - chunk; if (m > 64) m = 64;

        int j = 0;
        for (; j + 4 <= m; j += 4) {
            const int   c0 = __shfl(p.x, j),     c1 = __shfl(p.x, j + 1);
            const int   c2 = __shfl(p.x, j + 2), c3 = __shfl(p.x, j + 3);
            const float v0 = __int_as_float(__shfl(p.y, j));
            const float v1 = __int_as_float(__shfl(p.y, j + 1));
            const float v2 = __int_as_float(__shfl(p.y, j + 2));
            const float v3 = __int_as_float(__shfl(p.y, j + 3));
            const unsigned g0 = src[(size_t)c0 * 64 + lane];
            const unsigned g1 = src[(size_t)c1 * 64 + lane];
            const unsigned g2 = src[(size_t)c2 * 64 + lane];
            const unsigned g3 = src[(size_t)c3 * 64 + lane];
            acc.x += v0 * __uint_as_float(g0 << 16);
            acc.y += v0 * __uint_as_float(g0 & 0xFFFF0000u);
            acc.x += v1 * __uint_as_float(g1 << 16);
            acc.y += v1 * __uint_as_float(g1 & 0xFFFF0000u);
            acc.x += v2 * __uint_as_float(g2 << 16);
            acc.y += v2 * __uint_as_float(g2 & 0xFFFF0000u);
            acc.x += v3 * __uint_as_float(g3 << 16);
            acc.y += v3 * __uint_as_float(g3 & 0xFFFF0000u);
        }
        for (; j < m; ++j) {
            const int   c = __shfl(p.x, j);
            const float v = __int_as_float(__shfl(p.y, j));
            const unsigned g = src[(size_t)c * 64 + lane];
            acc.x += v * __uint_as_float(g << 16);
            acc.y += v * __uint_as_float(g & 0xFFFF0000u);
        }
    }

    if (WRITE_DST) dst[(size_t)row * 64 + lane] = pack_bf16(acc.x, acc.y);

    const size_t o = (size_t)row * EMBED_DIM + (lane << 1);
    float2 bsv;
    if (HAS_BASE) bsv = *reinterpret_cast<const float2*>(base + o);
    else          bsv = *reinterpret_cast<const float2*>(sum + o);
    bsv.x = (bsv.x + acc.x) * scale;
    bsv.y = (bsv.y + acc.y) * scale;
    *reinterpret_cast<float2*>(sum + o) = bsv;
}

template<bool WRITE_DST, bool HAS_BASE>
__global__ __launch_bounds__(256) void csr_spmm_dual_bf(
    const int*  __restrict__ ptr_u, const int2* __restrict__ pairs_u,
    const unsigned* __restrict__ src_u, unsigned* __restrict__ dst_u,
    float* __restrict__ sum_u, const float* __restrict__ base_u,
    const int*  __restrict__ ptr_i, const int2* __restrict__ pairs_i,
    const unsigned* __restrict__ src_i, unsigned* __restrict__ dst_i,
    float* __restrict__ sum_i, const float* __restrict__ base_i,
    int GU, float scale)
{
    const int lane = threadIdx.x & 63;
    const int w = threadIdx.x >> 6;
    if ((int)blockIdx.x < GU) {
        const int row = blockIdx.x * 4 + w;
        if (row < NUM_USERS)
            spmm_row_bf<WRITE_DST, HAS_BASE>(ptr_u, pairs_u, src_u, dst_u, sum_u, base_u, row, lane, scale);
    } else {
        const int row = ((int)blockIdx.x - GU) * 4 + w;
        if (row < NUM_ITEMS)
            spmm_row_bf<WRITE_DST, HAS_BASE>(ptr_i, pairs_i, src_i, dst_i, sum_i, base_i, row, lane, scale);
    }
}

// ---------------- fallback (round-1 atomic path) ----------------

__global__ __launch_bounds__(256) void edge_spmm(
    const float* __restrict__ vals, const int* __restrict__ rows,
    const int* __restrict__ cols, const float* __restrict__ u_src,
    const float* __restrict__ i_src, float* __restrict__ u_dst,
    float* __restrict__ i_dst, int nnz)
{
    const int lane = threadIdx.x & 31;
    const int e = blockIdx.x * 8 + (threadIdx.x >> 5);
    if (e >= nnz) return;
    const float v = vals[e];
    const size_t ro = (size_t)rows[e] * EMBED_DIM + lane * 4;
    const size_t co = (size_t)cols[e] * EMBED_DIM + lane * 4;
    const float4 iv = *reinterpret_cast<const float4*>(i_src + co);
    const float4 uv = *reinterpret_cast<const float4*>(u_src + ro);
    atomicAdd(u_dst + ro + 0, v * iv.x); atomicAdd(u_dst + ro + 1, v * iv.y);
    atomicAdd(u_dst + ro + 2, v * iv.z); atomicAdd(u_dst + ro + 3, v * iv.w);
    atomicAdd(i_dst + co + 0, v * uv.x); atomicAdd(i_dst + co + 1, v * uv.y);
    atomicAdd(i_dst + co + 2, v * uv.z); atomicAdd(i_dst + co + 3, v * uv.w);
}

__global__ __launch_bounds__(256) void acc_scale(
    float* __restrict__ out, const float* __restrict__ x, long n, float scale)
{
    long i = ((long)blockIdx.x * blockDim.x + threadIdx.x) * 4;
    if (i >= n) return;
    float4 o = *reinterpret_cast<float4*>(out + i);
    float4 a = *reinterpret_cast<const float4*>(x + i);
    o.x = (o.x + a.x) * scale; o.y = (o.y + a.y) * scale;
    o.z = (o.z + a.z) * scale; o.w = (o.w + a.w) * scale;
    *reinterpret_cast<float4*>(out + i) = o;
}

// ---------------- launch ----------------

extern "C" void kernel_launch(void* const* d_in, const int* in_sizes, int n_in,
                              void* d_out, int out_size, void* d_ws, size_t ws_size,
                              hipStream_t stream)
{
    const float* user = (const float*)d_in[0];
    const float* item = (const float*)d_in[1];
    const float* vals = (const float*)d_in[2];
    const int*   rows = (const int*)d_in[3];
    const int*   cols = (const int*)d_in[4];

    const size_t UD = (size_t)NUM_USERS * EMBED_DIM;   // 12.8M
    const size_t ID = (size_t)NUM_ITEMS * EMBED_DIM;   //  6.4M

    float* out_u = (float*)d_out;
    float* out_i = out_u + UD;

    // ---- CSR-path workspace layout (bf16 tables as packed uints) ----
    char* ws = (char*)d_ws;
    unsigned* user_bf = (unsigned*)ws;              ws += UD * 2;
    unsigned* item_bf = (unsigned*)ws;              ws += ID * 2;
    unsigned* uA = (unsigned*)ws;                   ws += UD * 2;
    unsigned* uB = (unsigned*)ws;                   ws += UD * 2;
    unsigned* iA = (unsigned*)ws;                   ws += ID * 2;
    unsigned* iB = (unsigned*)ws;                   ws += ID * 2;
    int2* pairs_u = (int2*)ws;                      ws += (size_t)NNZ_COUNT * 8;
    int2* pairs_i = (int2*)ws;                      ws += (size_t)NNZ_COUNT * 8;
    int* ptr_u = (int*)ws;                          ws += (NUM_USERS + 1) * 4;
    int* cnt_u = (int*)ws;                          ws += NUM_USERS * 4;
    int* ptr_i = (int*)ws;                          ws += (NUM_ITEMS + 1) * 4;
    int* cnt_i = (int*)ws;                          ws += NUM_ITEMS * 4;
    int* part_u = (int*)ws;                         ws += 64 * 4;
    int* part_i = (int*)ws;                         ws += 64 * 4;
    const size_t REQ = (size_t)(ws - (char*)d_ws);  // ~149 MB

    const int EB = (NNZ_COUNT + 255) / 256;

    if (ws_size >= REQ) {
        // ---- prep: bf16 copies of the input tables ----
        to_bf16_kernel<<<(int)(UD / 8 / 256), 256, 0, stream>>>(user, user_bf, (int)(UD / 8));
        to_bf16_kernel<<<(int)(ID / 8 / 256), 256, 0, stream>>>(item, item_bf, (int)(ID / 8));

        // ---- CSR build ----
        hipMemsetAsync(cnt_u, 0, NUM_USERS * 4, stream);
        hipMemsetAsync(cnt_i, 0, NUM_ITEMS * 4, stream);
        histo_kernel<<<EB, 256, 0, stream>>>(rows, cols, cnt_u, cnt_i, NNZ_COUNT);

        const int NBU = (NUM_USERS + SCAN_CHUNK - 1) / SCAN_CHUNK;   // 25
        const int NBI = (NUM_ITEMS + SCAN_CHUNK - 1) / SCAN_CHUNK;   // 13
        scan_partial_sums<<<NBU, 256, 0, stream>>>(cnt_u, part_u, NUM_USERS);
        scan_partial_sums<<<NBI, 256, 0, stream>>>(cnt_i, part_i, NUM_ITEMS);
        scan_partials_kernel<<<1, 64, 0, stream>>>(part_u, ptr_u + NUM_USERS, NBU);
        scan_partials_kernel<<<1, 64, 0, stream>>>(part_i, ptr_i + NUM_ITEMS, NBI);
        scan_chunk_kernel<<<NBU, 256, 0, stream>>>(cnt_u, part_u, ptr_u, NUM_USERS);
        scan_chunk_kernel<<<NBI, 256, 0, stream>>>(cnt_i, part_i, ptr_i, NUM_ITEMS);

        scatter_kernel<<<EB, 256, 0, stream>>>(rows, cols, vals, cnt_u, cnt_i,
                                               pairs_u, pairs_i, NNZ_COUNT);

        const int GU = (NUM_USERS + 3) / 4;   // 25000
        const int GI = (NUM_ITEMS + 3) / 4;   // 12500

        // layer 1: src = bf16 inputs; sum initialized from fp32 base (fused copy)
        csr_spmm_dual_bf<true, true><<<GU + GI, 256, 0, stream>>>(
            ptr_u, pairs_u, item_bf, uA, out_u, user,
            ptr_i, pairs_i, user_bf, iA, out_i, item, GU, 1.0f);
        // layer 2
        csr_spmm_dual_bf<true, false><<<GU + GI, 256, 0, stream>>>(
            ptr_u, pairs_u, iA, uB, out_u, nullptr,
            ptr_i, pairs_i, uA, iB, out_i, nullptr, GU, 1.0f);
        // layer 3: no dst store needed; fold final /4
        csr_spmm_dual_bf<false, false><<<GU + GI, 256, 0, stream>>>(
            ptr_u, pairs_u, iB, uA, out_u, nullptr,
            ptr_i, pairs_i, uB, iA, out_i, nullptr, GU, 0.25f);
    } else {
        // ---- fallback: round-1 atomic path (fp32 buffers carved from ws) ----
        char* fw = (char*)d_ws;
        float* fuA = (float*)fw;                    fw += UD * 4;
        float* fuB = (float*)fw;                    fw += UD * 4;
        float* fiA = (float*)fw;                    fw += ID * 4;
        float* fiB = (float*)fw;                    fw += ID * 4;

        const int EDGE_BLOCKS = (NNZ_COUNT + 7) / 8;
        const int ACC_U = (int)(UD / 1024), ACC_I = (int)(ID / 1024);

        hipMemcpyAsync(out_u, user, UD * 4, hipMemcpyDeviceToDevice, stream);
        hipMemcpyAsync(out_i, item, ID * 4, hipMemcpyDeviceToDevice, stream);

        hipMemsetAsync(fuA, 0, UD * 4, stream);
        hipMemsetAsync(fiA, 0, ID * 4, stream);
        edge_spmm<<<EDGE_BLOCKS, 256, 0, stream>>>(vals, rows, cols, user, item, fuA, fiA, NNZ_COUNT);
        acc_scale<<<ACC_U, 256, 0, stream>>>(out_u, fuA, (long)UD, 1.0f);
        acc_scale<<<ACC_I, 256, 0, stream>>>(out_i, fiA, (long)ID, 1.0f);

        hipMemsetAsync(fuB, 0, UD * 4, stream);
        hipMemsetAsync(fiB, 0, ID * 4, stream);
        edge_spmm<<<EDGE_BLOCKS, 256, 0, stream>>>(vals, rows, cols, fuA, fiA, fuB, fiB, NNZ_COUNT);
        acc_scale<<<ACC_U, 256, 0, stream>>>(out_u, fuB, (long)UD, 1.0f);
        acc_scale<<<ACC_I, 256, 0, stream>>>(out_i, fiB, (long)ID, 1.0f);

        hipMemsetAsync(fuA, 0, UD * 4, stream);
        hipMemsetAsync(fiA, 0, ID * 4, stream);
        edge_spmm<<<EDGE_BLOCKS, 256, 0, stream>>>(vals, rows, cols, fuB, fiB, fuA, fiA, NNZ_COUNT);
        acc_scale<<<ACC_U, 256, 0, stream>>>(out_u, fuA, (long)UD, 0.25f);
        acc_scale<<<ACC_I, 256, 0, stream>>>(out_i, fiA, (long)ID, 0.25f);
    }
}

// Round 6
// 890.386 us; speedup vs baseline: 2.2527x; 1.2498x over previous
//
#include <hip/hip_runtime.h>

// LightGCN-style 3-layer bipartite propagation.
// R5: scatter_kernel 355us (random 8B writes -> 247MB WRITE_SIZE). R4 showed
// 587 GLOBAL cursors = atomic-contention cliff; fix here is LDS-aggregated
// multisplit: per-block LDS histograms (no global atomics), per-(bucket,block)
// offset scan, LDS-cursor scatter with bucket-contiguous runs, then R4's
// proven phase-B bucket_scatter (L2-resident spans). bf16 gather SpMM kept.

#define NUM_USERS 100000
#define NUM_ITEMS 50000
#define EMBED_DIM 128
#define NNZ_COUNT 2000000
#define SCAN_CHUNK 4096
#define NBUCK_U 391            // ceil(100000/256)
#define NBUCK_I 196            // ceil(50000/256)
#define EPB 8192               // edges per multisplit block
#define NBLK 245               // ceil(NNZ_COUNT/EPB)

// ---------------- bf16 helpers (manual RTNE) ----------------

__device__ __forceinline__ unsigned bf16_rnd(float f) {
    unsigned u = __float_as_uint(f);
    return (u + 0x7FFFu + ((u >> 16) & 1u)) >> 16;
}
__device__ __forceinline__ unsigned pack_bf16(float x, float y) {
    return bf16_rnd(x) | (bf16_rnd(y) << 16);
}

__global__ __launch_bounds__(256) void to_bf16_kernel(
    const float* __restrict__ a, unsigned* __restrict__ o, int n8)
{
    int i = blockIdx.x * 256 + threadIdx.x;
    if (i >= n8) return;
    const float4* a4 = reinterpret_cast<const float4*>(a);
    float4 x = a4[i * 2], y = a4[i * 2 + 1];
    uint4 r;
    r.x = pack_bf16(x.x, x.y); r.y = pack_bf16(x.z, x.w);
    r.z = pack_bf16(y.x, y.y); r.w = pack_bf16(y.z, y.w);
    reinterpret_cast<uint4*>(o)[i] = r;
}

// ---------------- CSR row-pointer build ----------------

__global__ __launch_bounds__(256) void histo_kernel(
    const int* __restrict__ rows, const int* __restrict__ cols,
    int* __restrict__ cnt_u, int* __restrict__ cnt_i, int nnz)
{
    int e = blockIdx.x * blockDim.x + threadIdx.x;
    if (e >= nnz) return;
    atomicAdd(&cnt_u[rows[e]], 1);
    atomicAdd(&cnt_i[cols[e]], 1);
}

__global__ __launch_bounds__(256) void scan_partial_sums(
    const int* __restrict__ cnt, int* __restrict__ partials, int n)
{
    const int base = blockIdx.x * SCAN_CHUNK;
    int s = 0;
    for (int i = threadIdx.x; i < SCAN_CHUNK; i += 256) {
        const int idx = base + i;
        if (idx < n) s += cnt[idx];
    }
    for (int d = 32; d; d >>= 1) s += __shfl_down(s, d);
    __shared__ int red[4];
    if ((threadIdx.x & 63) == 0) red[threadIdx.x >> 6] = s;
    __syncthreads();
    if (threadIdx.x == 0) partials[blockIdx.x] = red[0] + red[1] + red[2] + red[3];
}

__global__ void scan_partials_kernel(int* __restrict__ partials,
                                     int* __restrict__ ptr_n, int nb)
{
    if (threadIdx.x == 0) {
        int run = 0;
        for (int b = 0; b < nb; ++b) { int x = partials[b]; partials[b] = run; run += x; }
        *ptr_n = run;
    }
}

__global__ __launch_bounds__(256) void scan_chunk_kernel(
    int* __restrict__ cnt, const int* __restrict__ partials,
    int* __restrict__ ptr, int n)
{
    __shared__ int tsum[256];
    const int t = threadIdx.x;
    const int base = blockIdx.x * SCAN_CHUNK + t * 16;
    int v[16];
    int s = 0;
    for (int k = 0; k < 16; ++k) {
        const int idx = base + k;
        v[k] = (idx < n) ? cnt[idx] : 0;
        s += v[k];
    }
    tsum[t] = s;
    __syncthreads();
    for (int d = 1; d < 256; d <<= 1) {
        const int y = (t >= d) ? tsum[t - d] : 0;
        __syncthreads();
        tsum[t] += y;
        __syncthreads();
    }
    int off = partials[blockIdx.x] + tsum[t] - s;
    for (int k = 0; k < 16; ++k) {
        const int idx = base + k;
        if (idx < n) ptr[idx] = off;
        off += v[k];
    }
}

// ---------------- LDS-aggregated multisplit (phase A) ----------------
// Zero global atomics: per-block LDS histogram -> per-(bucket,block) counts.

__global__ __launch_bounds__(256) void msplit_hist(
    const int* __restrict__ rows, const int* __restrict__ cols,
    int* __restrict__ hist_u, int* __restrict__ hist_i)
{
    __shared__ int h[NBUCK_U + NBUCK_I];
    for (int i = threadIdx.x; i < NBUCK_U + NBUCK_I; i += 256) h[i] = 0;
    __syncthreads();
    const int base = blockIdx.x * EPB;
    const int end = min(base + EPB, NNZ_COUNT);
    for (int e = base + threadIdx.x; e < end; e += 256) {
        atomicAdd(&h[rows[e] >> 8], 1);
        atomicAdd(&h[NBUCK_U + (cols[e] >> 8)], 1);
    }
    __syncthreads();
    for (int b = threadIdx.x; b < NBUCK_U; b += 256)
        hist_u[b * NBLK + blockIdx.x] = h[b];
    for (int b = threadIdx.x; b < NBUCK_I; b += 256)
        hist_i[b * NBLK + blockIdx.x] = h[NBUCK_U + b];
}

// One block per bucket: exclusive scan over its NBLK counts + bucket CSR base.
// offs layout [blk * nbuck + bucket] so msplit_scatter's loads coalesce.
__global__ __launch_bounds__(256) void msplit_offsets(
    const int* __restrict__ hist_u, const int* __restrict__ hist_i,
    const int* __restrict__ ptr_u, const int* __restrict__ ptr_i,
    int* __restrict__ offs_u, int* __restrict__ offs_i)
{
    __shared__ int buf[256];
    int b = blockIdx.x;
    const int* hist; const int* ptr; int* offs; int nbuck;
    if (b < NBUCK_U) { hist = hist_u; ptr = ptr_u; offs = offs_u; nbuck = NBUCK_U; }
    else { b -= NBUCK_U; hist = hist_i; ptr = ptr_i; offs = offs_i; nbuck = NBUCK_I; }
    const int t = threadIdx.x;
    const int x = (t < NBLK) ? hist[b * NBLK + t] : 0;
    buf[t] = x;
    __syncthreads();
    for (int d = 1; d < 256; d <<= 1) {
        const int y = (t >= d) ? buf[t - d] : 0;
        __syncthreads();
        buf[t] += y;
        __syncthreads();
    }
    if (t < NBLK) offs[t * nbuck + b] = ptr[b << 8] + buf[t] - x;
}

// Scatter with LDS cursors: writes land in bucket-contiguous runs.
// u pack: col(16b) | local_row(8b)<<16 ; i pack: row(17b) | local_col(8b)<<17.
__global__ __launch_bounds__(256) void msplit_scatter(
    const int* __restrict__ rows, const int* __restrict__ cols,
    const float* __restrict__ vals,
    const int* __restrict__ offs_u, const int* __restrict__ offs_i,
    int2* __restrict__ stage_u, int2* __restrict__ stage_i)
{
    __shared__ int cu[NBUCK_U];
    __shared__ int ci[NBUCK_I];
    const int t = threadIdx.x;
    for (int b = t; b < NBUCK_U; b += 256) cu[b] = offs_u[blockIdx.x * NBUCK_U + b];
    for (int b = t; b < NBUCK_I; b += 256) ci[b] = offs_i[blockIdx.x * NBUCK_I + b];
    __syncthreads();
    const int base = blockIdx.x * EPB;
    const int end = min(base + EPB, NNZ_COUNT);
    for (int e = base + t; e < end; e += 256) {
        const int r = rows[e];
        const int c = cols[e];
        const int vb = __float_as_int(vals[e]);
        const int su = atomicAdd(&cu[r >> 8], 1);
        stage_u[su] = make_int2(c | ((r & 255) << 16), vb);
        const int si = atomicAdd(&ci[c >> 8], 1);
        stage_i[si] = make_int2(r | ((c & 255) << 17), vb);
    }
}

// Phase B: one block per bucket; per-row cursors in LDS; writes confined to
// the bucket's L2-resident CSR span. (Measured ~100us in R4 — not the issue.)
__global__ __launch_bounds__(256) void bucket_scatter(
    const int* __restrict__ ptr_u, const int2* __restrict__ stage_u,
    int2* __restrict__ pairs_u,
    const int* __restrict__ ptr_i, const int2* __restrict__ stage_i,
    int2* __restrict__ pairs_i)
{
    __shared__ int cur[256];
    const int t = threadIdx.x;
    int b = blockIdx.x;
    const bool uside = (b < NBUCK_U);
    const int* ptr; const int2* stage; int2* pairs; int n;
    if (uside) { ptr = ptr_u; stage = stage_u; pairs = pairs_u; n = NUM_USERS; }
    else       { b -= NBUCK_U; ptr = ptr_i; stage = stage_i; pairs = pairs_i; n = NUM_ITEMS; }
    const int first = b << 8;
    const int last  = min(first + 256, n);
    if (first + t < last) cur[t] = ptr[first + t];
    __syncthreads();
    const int beg = ptr[first];
    const int end = ptr[last];
    for (int idx = beg + t; idx < end; idx += 256) {
        const int2 s = stage[idx];
        const int local   = uside ? ((s.x >> 16) & 255) : ((s.x >> 17) & 255);
        const int payload = uside ? (s.x & 0xFFFF)      : (s.x & 0x1FFFF);
        const int slot = atomicAdd(&cur[local], 1);
        pairs[slot] = make_int2(payload, s.y);
    }
}

// ---------------- SpMM: one 64-lane wave per destination row ----------------

template<bool WRITE_DST, bool HAS_BASE>
__device__ __forceinline__ void spmm_row_bf(
    const int* __restrict__ ptr, const int2* __restrict__ pairs,
    const unsigned* __restrict__ src, unsigned* __restrict__ dst,
    float* __restrict__ sum, const float* __restrict__ base,
    int row, int lane, float scale)
{
    const int start = ptr[row];
    const int end   = ptr[row + 1];
    float2 acc = make_float2(0.f, 0.f);

    for (int chunk = start; chunk < end; chunk += 64) {
        const int idx = chunk + lane;
        int2 p = make_int2(0, 0);
        if (idx < end) p = pairs[idx];
        int m = end - chunk; if (m > 64) m = 64;

        int j = 0;
        for (; j + 4 <= m; j += 4) {
            const int   c0 = __shfl(p.x, j),     c1 = __shfl(p.x, j + 1);
            const int   c2 = __shfl(p.x, j + 2), c3 = __shfl(p.x, j + 3);
            const float v0 = __int_as_float(__shfl(p.y, j));
            const float v1 = __int_as_float(__shfl(p.y, j + 1));
            const float v2 = __int_as_float(__shfl(p.y, j + 2));
            const float v3 = __int_as_float(__shfl(p.y, j + 3));
            const unsigned g0 = src[(size_t)c0 * 64 + lane];
            const unsigned g1 = src[(size_t)c1 * 64 + lane];
            const unsigned g2 = src[(size_t)c2 * 64 + lane];
            const unsigned g3 = src[(size_t)c3 * 64 + lane];
            acc.x += v0 * __uint_as_float(g0 << 16);
            acc.y += v0 * __uint_as_float(g0 & 0xFFFF0000u);
            acc.x += v1 * __uint_as_float(g1 << 16);
            acc.y += v1 * __uint_as_float(g1 & 0xFFFF0000u);
            acc.x += v2 * __uint_as_float(g2 << 16);
            acc.y += v2 * __uint_as_float(g2 & 0xFFFF0000u);
            acc.x += v3 * __uint_as_float(g3 << 16);
            acc.y += v3 * __uint_as_float(g3 & 0xFFFF0000u);
        }
        for (; j < m; ++j) {
            const int   c = __shfl(p.x, j);
            const float v = __int_as_float(__shfl(p.y, j));
            const unsigned g = src[(size_t)c * 64 + lane];
            acc.x += v * __uint_as_float(g << 16);
            acc.y += v * __uint_as_float(g & 0xFFFF0000u);
        }
    }

    if (WRITE_DST) dst[(size_t)row * 64 + lane] = pack_bf16(acc.x, acc.y);

    const size_t o = (size_t)row * EMBED_DIM + (lane << 1);
    float2 bsv;
    if (HAS_BASE) bsv = *reinterpret_cast<const float2*>(base + o);
    else          bsv = *reinterpret_cast<const float2*>(sum + o);
    bsv.x = (bsv.x + acc.x) * scale;
    bsv.y = (bsv.y + acc.y) * scale;
    *reinterpret_cast<float2*>(sum + o) = bsv;
}

template<bool WRITE_DST, bool HAS_BASE>
__global__ __launch_bounds__(256) void csr_spmm_dual_bf(
    const int*  __restrict__ ptr_u, const int2* __restrict__ pairs_u,
    const unsigned* __restrict__ src_u, unsigned* __restrict__ dst_u,
    float* __restrict__ sum_u, const float* __restrict__ base_u,
    const int*  __restrict__ ptr_i, const int2* __restrict__ pairs_i,
    const unsigned* __restrict__ src_i, unsigned* __restrict__ dst_i,
    float* __restrict__ sum_i, const float* __restrict__ base_i,
    int GU, float scale)
{
    const int lane = threadIdx.x & 63;
    const int w = threadIdx.x >> 6;
    if ((int)blockIdx.x < GU) {
        const int row = blockIdx.x * 4 + w;
        if (row < NUM_USERS)
            spmm_row_bf<WRITE_DST, HAS_BASE>(ptr_u, pairs_u, src_u, dst_u, sum_u, base_u, row, lane, scale);
    } else {
        const int row = ((int)blockIdx.x - GU) * 4 + w;
        if (row < NUM_ITEMS)
            spmm_row_bf<WRITE_DST, HAS_BASE>(ptr_i, pairs_i, src_i, dst_i, sum_i, base_i, row, lane, scale);
    }
}

// ---------------- fallback (round-1 atomic path) ----------------

__global__ __launch_bounds__(256) void edge_spmm(
    const float* __restrict__ vals, const int* __restrict__ rows,
    const int* __restrict__ cols, const float* __restrict__ u_src,
    const float* __restrict__ i_src, float* __restrict__ u_dst,
    float* __restrict__ i_dst, int nnz)
{
    const int lane = threadIdx.x & 31;
    const int e = blockIdx.x * 8 + (threadIdx.x >> 5);
    if (e >= nnz) return;
    const float v = vals[e];
    const size_t ro = (size_t)rows[e] * EMBED_DIM + lane * 4;
    const size_t co = (size_t)cols[e] * EMBED_DIM + lane * 4;
    const float4 iv = *reinterpret_cast<const float4*>(i_src + co);
    const float4 uv = *reinterpret_cast<const float4*>(u_src + ro);
    atomicAdd(u_dst + ro + 0, v * iv.x); atomicAdd(u_dst + ro + 1, v * iv.y);
    atomicAdd(u_dst + ro + 2, v * iv.z); atomicAdd(u_dst + ro + 3, v * iv.w);
    atomicAdd(i_dst + co + 0, v * uv.x); atomicAdd(i_dst + co + 1, v * uv.y);
    atomicAdd(i_dst + co + 2, v * uv.z); atomicAdd(i_dst + co + 3, v * uv.w);
}

__global__ __launch_bounds__(256) void acc_scale(
    float* __restrict__ out, const float* __restrict__ x, long n, float scale)
{
    long i = ((long)blockIdx.x * blockDim.x + threadIdx.x) * 4;
    if (i >= n) return;
    float4 o = *reinterpret_cast<float4*>(out + i);
    float4 a = *reinterpret_cast<const float4*>(x + i);
    o.x = (o.x + a.x) * scale; o.y = (o.y + a.y) * scale;
    o.z = (o.z + a.z) * scale; o.w = (o.w + a.w) * scale;
    *reinterpret_cast<float4*>(out + i) = o;
}

// ---------------- launch ----------------

extern "C" void kernel_launch(void* const* d_in, const int* in_sizes, int n_in,
                              void* d_out, int out_size, void* d_ws, size_t ws_size,
                              hipStream_t stream)
{
    const float* user = (const float*)d_in[0];
    const float* item = (const float*)d_in[1];
    const float* vals = (const float*)d_in[2];
    const int*   rows = (const int*)d_in[3];
    const int*   cols = (const int*)d_in[4];

    const size_t UD = (size_t)NUM_USERS * EMBED_DIM;   // 12.8M
    const size_t ID = (size_t)NUM_ITEMS * EMBED_DIM;   //  6.4M

    float* out_u = (float*)d_out;
    float* out_i = out_u + UD;

    // ---- CSR-path workspace layout ----
    char* ws = (char*)d_ws;
    unsigned* user_bf = (unsigned*)ws;              ws += UD * 2;
    unsigned* item_bf = (unsigned*)ws;              ws += ID * 2;
    unsigned* uA = (unsigned*)ws;                   ws += UD * 2;
    unsigned* uB = (unsigned*)ws;                   ws += UD * 2;
    unsigned* iA = (unsigned*)ws;                   ws += ID * 2;
    unsigned* iB = (unsigned*)ws;                   ws += ID * 2;
    int2* pairs_u = (int2*)ws;                      ws += (size_t)NNZ_COUNT * 8;
    int2* pairs_i = (int2*)ws;                      ws += (size_t)NNZ_COUNT * 8;
    int2* stage_u = (int2*)ws;                      ws += (size_t)NNZ_COUNT * 8;
    int2* stage_i = (int2*)ws;                      ws += (size_t)NNZ_COUNT * 8;
    int* ptr_u = (int*)ws;                          ws += (NUM_USERS + 1) * 4;
    int* cnt_u = (int*)ws;                          ws += NUM_USERS * 4;
    int* ptr_i = (int*)ws;                          ws += (NUM_ITEMS + 1) * 4;
    int* cnt_i = (int*)ws;                          ws += NUM_ITEMS * 4;
    int* part_u = (int*)ws;                         ws += 64 * 4;
    int* part_i = (int*)ws;                         ws += 64 * 4;
    const size_t REQ = (size_t)(ws - (char*)d_ws);  // ~180.4 MB (== R4's proven fit)

    // hist/offs (1.15 MB) alias into pairs_u: consumed by msplit_* before
    // bucket_scatter ever writes pairs_u (disjoint lifetimes).
    int* hist_u = (int*)pairs_u;
    int* hist_i = hist_u + NBUCK_U * NBLK;
    int* offs_u = hist_i + NBUCK_I * NBLK;
    int* offs_i = offs_u + NBLK * NBUCK_U;

    const int EB = (NNZ_COUNT + 255) / 256;

    if (ws_size >= REQ) {
        // ---- prep: bf16 copies of the input tables ----
        to_bf16_kernel<<<(int)(UD / 8 / 256), 256, 0, stream>>>(user, user_bf, (int)(UD / 8));
        to_bf16_kernel<<<(int)(ID / 8 / 256), 256, 0, stream>>>(item, item_bf, (int)(ID / 8));

        // ---- CSR row pointers ----
        hipMemsetAsync(cnt_u, 0, NUM_USERS * 4, stream);
        hipMemsetAsync(cnt_i, 0, NUM_ITEMS * 4, stream);
        histo_kernel<<<EB, 256, 0, stream>>>(rows, cols, cnt_u, cnt_i, NNZ_COUNT);

        const int NBU = (NUM_USERS + SCAN_CHUNK - 1) / SCAN_CHUNK;   // 25
        const int NBI = (NUM_ITEMS + SCAN_CHUNK - 1) / SCAN_CHUNK;   // 13
        scan_partial_sums<<<NBU, 256, 0, stream>>>(cnt_u, part_u, NUM_USERS);
        scan_partial_sums<<<NBI, 256, 0, stream>>>(cnt_i, part_i, NUM_ITEMS);
        scan_partials_kernel<<<1, 64, 0, stream>>>(part_u, ptr_u + NUM_USERS, NBU);
        scan_partials_kernel<<<1, 64, 0, stream>>>(part_i, ptr_i + NUM_ITEMS, NBI);
        scan_chunk_kernel<<<NBU, 256, 0, stream>>>(cnt_u, part_u, ptr_u, NUM_USERS);
        scan_chunk_kernel<<<NBI, 256, 0, stream>>>(cnt_i, part_i, ptr_i, NUM_ITEMS);

        // ---- LDS-aggregated multisplit + bucket-local scatter ----
        msplit_hist<<<NBLK, 256, 0, stream>>>(rows, cols, hist_u, hist_i);
        msplit_offsets<<<NBUCK_U + NBUCK_I, 256, 0, stream>>>(
            hist_u, hist_i, ptr_u, ptr_i, offs_u, offs_i);
        msplit_scatter<<<NBLK, 256, 0, stream>>>(
            rows, cols, vals, offs_u, offs_i, stage_u, stage_i);
        bucket_scatter<<<NBUCK_U + NBUCK_I, 256, 0, stream>>>(
            ptr_u, stage_u, pairs_u, ptr_i, stage_i, pairs_i);

        const int GU = (NUM_USERS + 3) / 4;   // 25000
        const int GI = (NUM_ITEMS + 3) / 4;   // 12500

        // layer 1: src = bf16 inputs; sum initialized from fp32 base (fused copy)
        csr_spmm_dual_bf<true, true><<<GU + GI, 256, 0, stream>>>(
            ptr_u, pairs_u, item_bf, uA, out_u, user,
            ptr_i, pairs_i, user_bf, iA, out_i, item, GU, 1.0f);
        // layer 2
        csr_spmm_dual_bf<true, false><<<GU + GI, 256, 0, stream>>>(
            ptr_u, pairs_u, iA, uB, out_u, nullptr,
            ptr_i, pairs_i, uA, iB, out_i, nullptr, GU, 1.0f);
        // layer 3: no dst store needed; fold final /4
        csr_spmm_dual_bf<false, false><<<GU + GI, 256, 0, stream>>>(
            ptr_u, pairs_u, iB, uA, out_u, nullptr,
            ptr_i, pairs_i, uB, iA, out_i, nullptr, GU, 0.25f);
    } else {
        // ---- fallback: round-1 atomic path (fp32 buffers carved from ws) ----
        char* fw = (char*)d_ws;
        float* fuA = (float*)fw;                    fw += UD * 4;
        float* fuB = (float*)fw;                    fw += UD * 4;
        float* fiA = (float*)fw;                    fw += ID * 4;
        float* fiB = (float*)fw;                    fw += ID * 4;

        const int EDGE_BLOCKS = (NNZ_COUNT + 7) / 8;
        const int ACC_U = (int)(UD / 1024), ACC_I = (int)(ID / 1024);

        hipMemcpyAsync(out_u, user, UD * 4, hipMemcpyDeviceToDevice, stream);
        hipMemcpyAsync(out_i, item, ID * 4, hipMemcpyDeviceToDevice, stream);

        hipMemsetAsync(fuA, 0, UD * 4, stream);
        hipMemsetAsync(fiA, 0, ID * 4, stream);
        edge_spmm<<<EDGE_BLOCKS, 256, 0, stream>>>(vals, rows, cols, user, item, fuA, fiA, NNZ_COUNT);
        acc_scale<<<ACC_U, 256, 0, stream>>>(out_u, fuA, (long)UD, 1.0f);
        acc_scale<<<ACC_I, 256, 0, stream>>>(out_i, fiA, (long)ID, 1.0f);

        hipMemsetAsync(fuB, 0, UD * 4, stream);
        hipMemsetAsync(fiB, 0, ID * 4, stream);
        edge_spmm<<<EDGE_BLOCKS, 256, 0, stream>>>(vals, rows, cols, fuA, fiA, fuB, fiB, NNZ_COUNT);
        acc_scale<<<ACC_U, 256, 0, stream>>>(out_u, fuB, (long)UD, 1.0f);
        acc_scale<<<ACC_I, 256, 0, stream>>>(out_i, fiB, (long)ID, 1.0f);

        hipMemsetAsync(fuA, 0, UD * 4, stream);
        hipMemsetAsync(fiA, 0, ID * 4, stream);
        edge_spmm<<<EDGE_BLOCKS, 256, 0, stream>>>(vals, rows, cols, fuB, fiB, fuA, fiA, NNZ_COUNT);
        acc_scale<<<ACC_U, 256, 0, stream>>>(out_u, fuA, (long)UD, 0.25f);
        acc_scale<<<ACC_I, 256, 0, stream>>>(out_i, fiA, (long)ID, 0.25f);
    }
}